// Round 2
// baseline (1099.545 us; speedup 1.0000x reference)
//
#include <hip/hip_runtime.h>
#include <hip/hip_bf16.h>

typedef unsigned short u16;
typedef unsigned int   u32;
typedef __attribute__((ext_vector_type(8))) short short8;
typedef __attribute__((ext_vector_type(4))) float floatx4;

__device__ __forceinline__ float bits2f(u32 v){ float f; __builtin_memcpy(&f, &v, 4); return f; }
__device__ __forceinline__ u16 f2bf(float f){
    __hip_bfloat16 h = __float2bfloat16(f);
    u16 u; __builtin_memcpy(&u, &h, 2); return u;
}

// ---------------- f32 -> bf16 conversion (x into hbuf) ----------------

__global__ __launch_bounds__(256) void cvt_kernel(const float* __restrict__ in,
                                                  u16* __restrict__ out, int total4){
    int i = blockIdx.x * 256 + threadIdx.x;   // total4 = n_elems / 4
    if (i >= total4) return;
    float4 v = ((const float4*)in)[i];
    uint2 o;
    o.x = (u32)f2bf(v.x) | ((u32)f2bf(v.y) << 16);
    o.y = (u32)f2bf(v.z) | ((u32)f2bf(v.w) << 16);
    ((uint2*)out)[i] = o;
}

// ---------------- CSR build ----------------

__global__ void hist_kernel(const int* __restrict__ dst, int* __restrict__ cnt, int E){
    int i = blockIdx.x * 256 + threadIdx.x;
    if (i < E) atomicAdd(&cnt[dst[i]], 1);
}

__global__ __launch_bounds__(1024) void scan_chunk_kernel(const int* __restrict__ cnt,
                                                          int* __restrict__ scn,
                                                          int* __restrict__ bsum, int Nn){
    __shared__ int buf[2][1024];
    int i = blockIdx.x * 1024 + threadIdx.x;
    int v = (i < Nn) ? cnt[i] : 0;
    int pb = 0;
    buf[0][threadIdx.x] = v;
    __syncthreads();
    for (int off = 1; off < 1024; off <<= 1){
        int nv = buf[pb][threadIdx.x];
        if ((int)threadIdx.x >= off) nv += buf[pb][threadIdx.x - off];
        buf[1 - pb][threadIdx.x] = nv;
        pb ^= 1;
        __syncthreads();
    }
    int inc = buf[pb][threadIdx.x];
    if (i < Nn) scn[i] = inc;
    if (threadIdx.x == 1023) bsum[blockIdx.x] = inc;
}

__global__ __launch_bounds__(1024) void scan_sums_kernel(int* __restrict__ bsum, int NB){
    __shared__ int buf[2][1024];
    int t = threadIdx.x;
    int v = (t < NB) ? bsum[t] : 0;
    int pb = 0;
    buf[0][t] = v;
    __syncthreads();
    for (int off = 1; off < 1024; off <<= 1){
        int nv = buf[pb][t];
        if (t >= off) nv += buf[pb][t - off];
        buf[1 - pb][t] = nv;
        pb ^= 1;
        __syncthreads();
    }
    if (t < NB) bsum[t] = buf[pb][t] - v;   // exclusive block offset
}

__global__ void finalize_kernel(const int* __restrict__ cnt, const int* __restrict__ scn,
                                const int* __restrict__ bsum, int* __restrict__ indptr,
                                int* __restrict__ cursor, float* __restrict__ invdeg, int Nn){
    int i = blockIdx.x * 256 + threadIdx.x;
    if (i >= Nn) return;
    int incl = scn[i] + bsum[i >> 10];
    indptr[i + 1] = incl;
    int c = cnt[i];
    cursor[i] = incl - c;
    invdeg[i] = 1.0f / (float)max(c, 1);
    if (i == 0) indptr[0] = 0;
}

__global__ void fill_kernel(const int* __restrict__ src, const int* __restrict__ dst,
                            int* __restrict__ cursor, int* __restrict__ esrc, int E){
    int i = blockIdx.x * 256 + threadIdx.x;
    if (i < E){
        int p = atomicAdd(&cursor[dst[i]], 1);
        esrc[p] = src[i];
    }
}

// ------- weight packing (f32 in, bf16 out): Bpack[n][k] = k<128 ? w_self[k][n] : w_neigh[k-128][n] -------

__global__ void pack_kernel(const float* __restrict__ wself, const float* __restrict__ wneigh,
                            u16* __restrict__ bp, int N){
    int i = blockIdx.x * 256 + threadIdx.x;
    if (i >= N * 256) return;
    int n = i >> 8, k = i & 255;
    float v = (k < 128) ? wself[k * N + n] : wneigh[(k - 128) * N + n];
    bp[i] = f2bf(v);
}

// ---------------- aggregation: agg[n] = (1/max(deg,1)) * sum_{e in CSR[n]} h[esrc[e]]  (bf16 h) ----------------

__global__ __launch_bounds__(256) void agg_kernel(const u16* __restrict__ h,
                                                  const int* __restrict__ indptr,
                                                  const int* __restrict__ esrc,
                                                  const float* __restrict__ invdeg,
                                                  u16* __restrict__ agg, int M){
    const int wave = threadIdx.x >> 6;
    const int lane = threadIdx.x & 63;
    const int n = blockIdx.x * 4 + wave;
    if (n >= M) return;
    const int beg = indptr[n], end = indptr[n + 1];
    float s0 = 0.f, s1 = 0.f;
    for (int e = beg; e < end; ++e){
        int sidx = esrc[e];
        u32 v = *(const u32*)(h + (size_t)sidx * 128 + lane * 2);
        s0 += bits2f(v << 16);
        s1 += bits2f(v & 0xffff0000u);
    }
    float sc = invdeg[n];
    u32 o = (u32)f2bf(s0 * sc) | ((u32)f2bf(s1 * sc) << 16);
    *(u32*)(agg + (size_t)n * 128 + lane * 2) = o;
}

// ------- fused GEMM: out[M][N] = [h | agg] @ Bpack^T + bias  (K=256, bf16 MFMA, f32 bias/out) -------

__global__ __launch_bounds__(256) void gemm_kernel(const u16* __restrict__ hA,
                                                   const u16* __restrict__ aggA,
                                                   const u16* __restrict__ Bp,
                                                   const float* __restrict__ bias,
                                                   float* __restrict__ out, int M, int N){
    const int wave = threadIdx.x >> 6;
    const int lane = threadIdx.x & 63;
    const int m15 = lane & 15;
    const int quad = lane >> 4;
    const int rowbase = blockIdx.x * 64 + wave * 16;
    const int colbase = blockIdx.y * 64;

    floatx4 acc[4];
    #pragma unroll
    for (int i = 0; i < 4; ++i) acc[i] = 0.0f;

    int arow = rowbase + m15;
    if (arow >= M) arow = M - 1;
    const u16* a0 = hA   + (size_t)arow * 128 + quad * 8;
    const u16* a1 = aggA + (size_t)arow * 128 + quad * 8;

    #pragma unroll
    for (int k0 = 0; k0 < 256; k0 += 32){
        const u16* ap = (k0 < 128) ? (a0 + k0) : (a1 + (k0 - 128));
        short8 a = *(const short8*)ap;
        #pragma unroll
        for (int nt = 0; nt < 4; ++nt){
            const u16* bp = Bp + (size_t)(colbase + nt * 16 + m15) * 256 + k0 + quad * 8;
            short8 b = *(const short8*)bp;
            acc[nt] = __builtin_amdgcn_mfma_f32_16x16x32_bf16(a, b, acc[nt], 0, 0, 0);
        }
    }

    const int orow = rowbase + quad * 4;
    #pragma unroll
    for (int nt = 0; nt < 4; ++nt){
        int col = colbase + nt * 16 + m15;
        float bv = bias[col];
        #pragma unroll
        for (int r = 0; r < 4; ++r){
            int row = orow + r;
            if (row < M) out[(size_t)row * N + col] = acc[nt][r] + bv;
        }
    }
}

// ---------------- BatchNorm stats / finalize / apply(+ReLU, bf16 pack) ----------------

__global__ __launch_bounds__(256) void stats_kernel(const float* __restrict__ pre,
                                                    float* __restrict__ cs, int M){
    const int c = threadIdx.x & 127;
    const int half = threadIdx.x >> 7;
    int r0 = blockIdx.x * 400;
    int r1 = min(r0 + 400, M);
    float s = 0.f, s2 = 0.f;
    for (int r = r0 + half; r < r1; r += 2){
        float v = pre[(size_t)r * 128 + c];
        s += v;
        s2 = fmaf(v, v, s2);
    }
    atomicAdd(&cs[c], s);
    atomicAdd(&cs[128 + c], s2);
}

__global__ void bnfin_kernel(float* __restrict__ cs, const float* __restrict__ gamma,
                             const float* __restrict__ beta, float invM){
    int c = threadIdx.x;  // 128 threads
    float mu  = cs[c] * invM;
    float var = fmaxf(cs[128 + c] * invM - mu * mu, 0.0f);
    float sc  = gamma[c] * rsqrtf(var + 1e-5f);
    cs[256 + c] = sc;
    cs[384 + c] = beta[c] - mu * sc;
}

__global__ __launch_bounds__(256) void apply_kernel(const float* __restrict__ pre,
                                                    const float* __restrict__ cs,
                                                    u16* __restrict__ hout, int total){
    int i = blockIdx.x * 256 + threadIdx.x;  // total = M*128/4
    if (i >= total) return;
    float4 v = ((const float4*)pre)[i];
    int c = (i & 31) * 4;
    float r0 = fmaxf(fmaf(v.x, cs[256 + c + 0], cs[384 + c + 0]), 0.f);
    float r1 = fmaxf(fmaf(v.y, cs[256 + c + 1], cs[384 + c + 1]), 0.f);
    float r2 = fmaxf(fmaf(v.z, cs[256 + c + 2], cs[384 + c + 2]), 0.f);
    float r3 = fmaxf(fmaf(v.w, cs[256 + c + 3], cs[384 + c + 3]), 0.f);
    uint2 o;
    o.x = (u32)f2bf(r0) | ((u32)f2bf(r1) << 16);
    o.y = (u32)f2bf(r2) | ((u32)f2bf(r3) << 16);
    ((uint2*)hout)[i] = o;
}

// ---------------- log_softmax over rows of 64 (one wave per row, f32 out) ----------------

__global__ __launch_bounds__(256) void lsm_kernel(const float* __restrict__ pre,
                                                  float* __restrict__ out, int M){
    const int wave = threadIdx.x >> 6;
    const int lane = threadIdx.x & 63;
    const int row = blockIdx.x * 4 + wave;
    if (row >= M) return;
    float v = pre[(size_t)row * 64 + lane];
    float m = v;
    #pragma unroll
    for (int o = 32; o; o >>= 1) m = fmaxf(m, __shfl_xor(m, o));
    float e = __expf(v - m);
    float s = e;
    #pragma unroll
    for (int o = 32; o; o >>= 1) s += __shfl_xor(s, o);
    out[(size_t)row * 64 + lane] = v - m - __logf(s);
}

// ---------------- host ----------------

extern "C" void kernel_launch(void* const* d_in, const int* in_sizes, int n_in,
                              void* d_out, int out_size, void* d_ws, size_t ws_size,
                              hipStream_t stream) {
    const float* x   = (const float*)d_in[0];
    const int*   src = (const int*)d_in[1];
    const int*   dst = (const int*)d_in[2];
    const float* wself[3]  = {(const float*)d_in[3], (const float*)d_in[6], (const float*)d_in[9]};
    const float* wneigh[3] = {(const float*)d_in[4], (const float*)d_in[7], (const float*)d_in[10]};
    const float* bias[3]   = {(const float*)d_in[5], (const float*)d_in[8], (const float*)d_in[11]};
    const float* gamma[2]  = {(const float*)d_in[12], (const float*)d_in[14]};
    const float* beta[2]   = {(const float*)d_in[13], (const float*)d_in[15]};

    const int M = in_sizes[0] / 128;   // 100000
    const int E = in_sizes[1];         // 1600000

    char* ws = (char*)d_ws;
    size_t off = 0;
    auto alloc = [&](size_t bytes) -> void* {
        void* p = ws + off;
        off = (off + bytes + 511) & ~(size_t)511;
        return p;
    };
    int*   cnt    = (int*)alloc((size_t)M * 4);
    int*   indptr = (int*)alloc((size_t)(M + 1) * 4);
    int*   cursor = (int*)alloc((size_t)M * 4);
    int*   scn    = (int*)alloc((size_t)M * 4);
    int*   bsum   = (int*)alloc(1024 * 4);
    int*   esrc   = (int*)alloc((size_t)E * 4);
    float* invdeg = (float*)alloc((size_t)M * 4);
    u16* bpack0 = (u16*)alloc(128 * 256 * 2);
    u16* bpack1 = (u16*)alloc(128 * 256 * 2);
    u16* bpack2 = (u16*)alloc(64 * 256 * 2);
    const u16* bpack[3] = {bpack0, bpack1, bpack2};
    float* colstat = (float*)alloc(512 * 4);
    u16*   hbuf    = (u16*)alloc((size_t)M * 128 * 2);  // also holds bf16(x) for layer 0
    u16*   aggbuf  = (u16*)alloc((size_t)M * 128 * 2);
    float* pre     = (float*)alloc((size_t)M * 128 * 4);

    // --- CSR build (once per call; ws is re-poisoned every launch) ---
    hipMemsetAsync(cnt, 0, (size_t)M * 4, stream);
    hist_kernel<<<(E + 255) / 256, 256, 0, stream>>>(dst, cnt, E);
    int NB = (M + 1023) / 1024;
    scan_chunk_kernel<<<NB, 1024, 0, stream>>>(cnt, scn, bsum, M);
    scan_sums_kernel<<<1, 1024, 0, stream>>>(bsum, NB);
    finalize_kernel<<<(M + 255) / 256, 256, 0, stream>>>(cnt, scn, bsum, indptr, cursor, invdeg, M);
    fill_kernel<<<(E + 255) / 256, 256, 0, stream>>>(src, dst, cursor, esrc, E);

    // --- convert x (f32) to bf16 into hbuf; pack weights f32->bf16 B[n][k] ---
    cvt_kernel<<<((M * 32) + 255) / 256, 256, 0, stream>>>(x, hbuf, M * 32);
    pack_kernel<<<(128 * 256 + 255) / 256, 256, 0, stream>>>(wself[0], wneigh[0], bpack0, 128);
    pack_kernel<<<(128 * 256 + 255) / 256, 256, 0, stream>>>(wself[1], wneigh[1], bpack1, 128);
    pack_kernel<<<(64 * 256 + 255) / 256, 256, 0, stream>>>(wself[2], wneigh[2], bpack2, 64);

    const u16* h = hbuf;
    for (int l = 0; l < 2; ++l){
        agg_kernel<<<(M + 3) / 4, 256, 0, stream>>>(h, indptr, esrc, invdeg, aggbuf, M);
        gemm_kernel<<<dim3((M + 63) / 64, 2), 256, 0, stream>>>(h, aggbuf, bpack[l], bias[l], pre, M, 128);
        hipMemsetAsync(colstat, 0, 256 * 4, stream);
        stats_kernel<<<(M + 399) / 400, 256, 0, stream>>>(pre, colstat, M);
        bnfin_kernel<<<1, 128, 0, stream>>>(colstat, gamma[l], beta[l], 1.0f / (float)M);
        apply_kernel<<<((M * 32) + 255) / 256, 256, 0, stream>>>(pre, colstat, hbuf, M * 32);
        h = hbuf;
    }
    agg_kernel<<<(M + 3) / 4, 256, 0, stream>>>(h, indptr, esrc, invdeg, aggbuf, M);
    gemm_kernel<<<dim3((M + 63) / 64, 1), 256, 0, stream>>>(h, aggbuf, bpack[2], bias[2], pre, M, 64);
    lsm_kernel<<<(M + 3) / 4, 256, 0, stream>>>(pre, (float*)d_out, M);
}

// Round 3
// 868.692 us; speedup vs baseline: 1.2657x; 1.2657x over previous
//
#include <hip/hip_runtime.h>
#include <hip/hip_bf16.h>

typedef unsigned short u16;
typedef unsigned int   u32;
typedef __attribute__((ext_vector_type(8))) short short8;
typedef __attribute__((ext_vector_type(4))) float floatx4;

__device__ __forceinline__ float bits2f(u32 v){ float f; __builtin_memcpy(&f, &v, 4); return f; }
__device__ __forceinline__ u16 f2bf(float f){
    __hip_bfloat16 h = __float2bfloat16(f);
    u16 u; __builtin_memcpy(&u, &h, 2); return u;
}

// ---------------- f32 -> bf16 conversion (x into hbuf) ----------------

__global__ __launch_bounds__(256) void cvt_kernel(const float* __restrict__ in,
                                                  u16* __restrict__ out, int total4){
    int i = blockIdx.x * 256 + threadIdx.x;   // total4 = n_elems / 4
    if (i >= total4) return;
    float4 v = ((const float4*)in)[i];
    uint2 o;
    o.x = (u32)f2bf(v.x) | ((u32)f2bf(v.y) << 16);
    o.y = (u32)f2bf(v.z) | ((u32)f2bf(v.w) << 16);
    ((uint2*)out)[i] = o;
}

// ---------------- CSR build ----------------

__global__ void hist_kernel(const int* __restrict__ dst, int* __restrict__ cnt, int E){
    int i = blockIdx.x * 256 + threadIdx.x;
    if (i < E) atomicAdd(&cnt[dst[i]], 1);
}

__global__ __launch_bounds__(1024) void scan_chunk_kernel(const int* __restrict__ cnt,
                                                          int* __restrict__ scn,
                                                          int* __restrict__ bsum, int Nn){
    __shared__ int buf[2][1024];
    int i = blockIdx.x * 1024 + threadIdx.x;
    int v = (i < Nn) ? cnt[i] : 0;
    int pb = 0;
    buf[0][threadIdx.x] = v;
    __syncthreads();
    for (int off = 1; off < 1024; off <<= 1){
        int nv = buf[pb][threadIdx.x];
        if ((int)threadIdx.x >= off) nv += buf[pb][threadIdx.x - off];
        buf[1 - pb][threadIdx.x] = nv;
        pb ^= 1;
        __syncthreads();
    }
    int inc = buf[pb][threadIdx.x];
    if (i < Nn) scn[i] = inc;
    if (threadIdx.x == 1023) bsum[blockIdx.x] = inc;
}

__global__ __launch_bounds__(1024) void scan_sums_kernel(int* __restrict__ bsum, int NB){
    __shared__ int buf[2][1024];
    int t = threadIdx.x;
    int v = (t < NB) ? bsum[t] : 0;
    int pb = 0;
    buf[0][t] = v;
    __syncthreads();
    for (int off = 1; off < 1024; off <<= 1){
        int nv = buf[pb][t];
        if (t >= off) nv += buf[pb][t - off];
        buf[1 - pb][t] = nv;
        pb ^= 1;
        __syncthreads();
    }
    if (t < NB) bsum[t] = buf[pb][t] - v;   // exclusive block offset
}

__global__ void finalize_kernel(const int* __restrict__ cnt, const int* __restrict__ scn,
                                const int* __restrict__ bsum, int* __restrict__ indptr,
                                int* __restrict__ cursor, float* __restrict__ invdeg, int Nn){
    int i = blockIdx.x * 256 + threadIdx.x;
    if (i >= Nn) return;
    int incl = scn[i] + bsum[i >> 10];
    indptr[i + 1] = incl;
    int c = cnt[i];
    cursor[i] = incl - c;
    invdeg[i] = 1.0f / (float)max(c, 1);
    if (i == 0) indptr[0] = 0;
}

__global__ void fill_kernel(const int* __restrict__ src, const int* __restrict__ dst,
                            int* __restrict__ cursor, int* __restrict__ esrc, int E){
    int i = blockIdx.x * 256 + threadIdx.x;
    if (i < E){
        int p = atomicAdd(&cursor[dst[i]], 1);
        esrc[p] = src[i];
    }
}

// ------- weight packing (f32 in, bf16 out): Bpack[n][k] = k<128 ? w_self[k][n] : w_neigh[k-128][n] -------

__global__ void pack_kernel(const float* __restrict__ wself, const float* __restrict__ wneigh,
                            u16* __restrict__ bp, int N){
    int i = blockIdx.x * 256 + threadIdx.x;
    if (i >= N * 256) return;
    int n = i >> 8, k = i & 255;
    float v = (k < 128) ? wself[k * N + n] : wneigh[(k - 128) * N + n];
    bp[i] = f2bf(v);
}

// ---------------- aggregation: agg[n] = (1/max(deg,1)) * sum_{e in CSR[n]} h[esrc[e]]  (bf16 h) -------
// One wave per node. 4 edge-groups of 16 lanes; each lane loads 16 B (8 bf16 channels)
// => one wave iteration covers 4 edges x 256 B = 1 KiB in flight per instruction.

__global__ __launch_bounds__(256) void agg_kernel(const u16* __restrict__ h,
                                                  const int* __restrict__ indptr,
                                                  const int* __restrict__ esrc,
                                                  const float* __restrict__ invdeg,
                                                  u16* __restrict__ agg, int M){
    const int wave = threadIdx.x >> 6;
    const int lane = threadIdx.x & 63;
    const int g    = lane >> 4;     // edge subgroup 0..3
    const int l16  = lane & 15;     // channel-chunk index (8 channels each)
    const int n = blockIdx.x * 4 + wave;
    if (n >= M) return;
    const int beg = indptr[n], end = indptr[n + 1];

    float s[8];
    #pragma unroll
    for (int i = 0; i < 8; ++i) s[i] = 0.f;

    #pragma unroll 2
    for (int e0 = beg; e0 < end; e0 += 4){
        int e = e0 + g;
        if (e < end){
            int sidx = esrc[e];
            uint4 v = *(const uint4*)(h + (size_t)sidx * 128 + l16 * 8);
            s[0] += bits2f(v.x << 16);  s[1] += bits2f(v.x & 0xffff0000u);
            s[2] += bits2f(v.y << 16);  s[3] += bits2f(v.y & 0xffff0000u);
            s[4] += bits2f(v.z << 16);  s[5] += bits2f(v.z & 0xffff0000u);
            s[6] += bits2f(v.w << 16);  s[7] += bits2f(v.w & 0xffff0000u);
        }
    }

    // combine the 4 edge subgroups (lanes l16, l16+16, l16+32, l16+48)
    #pragma unroll
    for (int i = 0; i < 8; ++i){
        s[i] += __shfl_xor(s[i], 16);
        s[i] += __shfl_xor(s[i], 32);
    }

    if (g == 0){
        float sc = invdeg[n];
        uint4 o;
        o.x = (u32)f2bf(s[0] * sc) | ((u32)f2bf(s[1] * sc) << 16);
        o.y = (u32)f2bf(s[2] * sc) | ((u32)f2bf(s[3] * sc) << 16);
        o.z = (u32)f2bf(s[4] * sc) | ((u32)f2bf(s[5] * sc) << 16);
        o.w = (u32)f2bf(s[6] * sc) | ((u32)f2bf(s[7] * sc) << 16);
        *(uint4*)(agg + (size_t)n * 128 + l16 * 8) = o;
    }
}

// ------- fused GEMM: out[M][N] = [h | agg] @ Bpack^T + bias  (K=256, bf16 MFMA, f32 bias/out) -------

__global__ __launch_bounds__(256) void gemm_kernel(const u16* __restrict__ hA,
                                                   const u16* __restrict__ aggA,
                                                   const u16* __restrict__ Bp,
                                                   const float* __restrict__ bias,
                                                   float* __restrict__ out, int M, int N){
    const int wave = threadIdx.x >> 6;
    const int lane = threadIdx.x & 63;
    const int m15 = lane & 15;
    const int quad = lane >> 4;
    const int rowbase = blockIdx.x * 64 + wave * 16;
    const int colbase = blockIdx.y * 64;

    floatx4 acc[4];
    #pragma unroll
    for (int i = 0; i < 4; ++i) acc[i] = 0.0f;

    int arow = rowbase + m15;
    if (arow >= M) arow = M - 1;
    const u16* a0 = hA   + (size_t)arow * 128 + quad * 8;
    const u16* a1 = aggA + (size_t)arow * 128 + quad * 8;

    #pragma unroll
    for (int k0 = 0; k0 < 256; k0 += 32){
        const u16* ap = (k0 < 128) ? (a0 + k0) : (a1 + (k0 - 128));
        short8 a = *(const short8*)ap;
        #pragma unroll
        for (int nt = 0; nt < 4; ++nt){
            const u16* bp = Bp + (size_t)(colbase + nt * 16 + m15) * 256 + k0 + quad * 8;
            short8 b = *(const short8*)bp;
            acc[nt] = __builtin_amdgcn_mfma_f32_16x16x32_bf16(a, b, acc[nt], 0, 0, 0);
        }
    }

    const int orow = rowbase + quad * 4;
    #pragma unroll
    for (int nt = 0; nt < 4; ++nt){
        int col = colbase + nt * 16 + m15;
        float bv = bias[col];
        #pragma unroll
        for (int r = 0; r < 4; ++r){
            int row = orow + r;
            if (row < M) out[(size_t)row * N + col] = acc[nt][r] + bv;
        }
    }
}

// ---------------- BatchNorm stats / finalize / apply(+ReLU, bf16 pack) ----------------

__global__ __launch_bounds__(256) void stats_kernel(const float* __restrict__ pre,
                                                    float* __restrict__ cs, int M){
    const int c = threadIdx.x & 127;
    const int half = threadIdx.x >> 7;
    int r0 = blockIdx.x * 400;
    int r1 = min(r0 + 400, M);
    float s = 0.f, s2 = 0.f;
    for (int r = r0 + half; r < r1; r += 2){
        float v = pre[(size_t)r * 128 + c];
        s += v;
        s2 = fmaf(v, v, s2);
    }
    atomicAdd(&cs[c], s);
    atomicAdd(&cs[128 + c], s2);
}

__global__ void bnfin_kernel(float* __restrict__ cs, const float* __restrict__ gamma,
                             const float* __restrict__ beta, float invM){
    int c = threadIdx.x;  // 128 threads
    float mu  = cs[c] * invM;
    float var = fmaxf(cs[128 + c] * invM - mu * mu, 0.0f);
    float sc  = gamma[c] * rsqrtf(var + 1e-5f);
    cs[256 + c] = sc;
    cs[384 + c] = beta[c] - mu * sc;
}

__global__ __launch_bounds__(256) void apply_kernel(const float* __restrict__ pre,
                                                    const float* __restrict__ cs,
                                                    u16* __restrict__ hout, int total){
    int i = blockIdx.x * 256 + threadIdx.x;  // total = M*128/4
    if (i >= total) return;
    float4 v = ((const float4*)pre)[i];
    int c = (i & 31) * 4;
    float r0 = fmaxf(fmaf(v.x, cs[256 + c + 0], cs[384 + c + 0]), 0.f);
    float r1 = fmaxf(fmaf(v.y, cs[256 + c + 1], cs[384 + c + 1]), 0.f);
    float r2 = fmaxf(fmaf(v.z, cs[256 + c + 2], cs[384 + c + 2]), 0.f);
    float r3 = fmaxf(fmaf(v.w, cs[256 + c + 3], cs[384 + c + 3]), 0.f);
    uint2 o;
    o.x = (u32)f2bf(r0) | ((u32)f2bf(r1) << 16);
    o.y = (u32)f2bf(r2) | ((u32)f2bf(r3) << 16);
    ((uint2*)hout)[i] = o;
}

// ---------------- log_softmax over rows of 64 (one wave per row, f32 out) ----------------

__global__ __launch_bounds__(256) void lsm_kernel(const float* __restrict__ pre,
                                                  float* __restrict__ out, int M){
    const int wave = threadIdx.x >> 6;
    const int lane = threadIdx.x & 63;
    const int row = blockIdx.x * 4 + wave;
    if (row >= M) return;
    float v = pre[(size_t)row * 64 + lane];
    float m = v;
    #pragma unroll
    for (int o = 32; o; o >>= 1) m = fmaxf(m, __shfl_xor(m, o));
    float e = __expf(v - m);
    float s = e;
    #pragma unroll
    for (int o = 32; o; o >>= 1) s += __shfl_xor(s, o);
    out[(size_t)row * 64 + lane] = v - m - __logf(s);
}

// ---------------- host ----------------

extern "C" void kernel_launch(void* const* d_in, const int* in_sizes, int n_in,
                              void* d_out, int out_size, void* d_ws, size_t ws_size,
                              hipStream_t stream) {
    const float* x   = (const float*)d_in[0];
    const int*   src = (const int*)d_in[1];
    const int*   dst = (const int*)d_in[2];
    const float* wself[3]  = {(const float*)d_in[3], (const float*)d_in[6], (const float*)d_in[9]};
    const float* wneigh[3] = {(const float*)d_in[4], (const float*)d_in[7], (const float*)d_in[10]};
    const float* bias[3]   = {(const float*)d_in[5], (const float*)d_in[8], (const float*)d_in[11]};
    const float* gamma[2]  = {(const float*)d_in[12], (const float*)d_in[14]};
    const float* beta[2]   = {(const float*)d_in[13], (const float*)d_in[15]};

    const int M = in_sizes[0] / 128;   // 100000
    const int E = in_sizes[1];         // 1600000

    char* ws = (char*)d_ws;
    size_t off = 0;
    auto alloc = [&](size_t bytes) -> void* {
        void* p = ws + off;
        off = (off + bytes + 511) & ~(size_t)511;
        return p;
    };
    int*   cnt    = (int*)alloc((size_t)M * 4);
    int*   indptr = (int*)alloc((size_t)(M + 1) * 4);
    int*   cursor = (int*)alloc((size_t)M * 4);
    int*   scn    = (int*)alloc((size_t)M * 4);
    int*   bsum   = (int*)alloc(1024 * 4);
    int*   esrc   = (int*)alloc((size_t)E * 4);
    float* invdeg = (float*)alloc((size_t)M * 4);
    u16* bpack0 = (u16*)alloc(128 * 256 * 2);
    u16* bpack1 = (u16*)alloc(128 * 256 * 2);
    u16* bpack2 = (u16*)alloc(64 * 256 * 2);
    const u16* bpack[3] = {bpack0, bpack1, bpack2};
    float* colstat = (float*)alloc(512 * 4);
    u16*   hbuf    = (u16*)alloc((size_t)M * 128 * 2);  // also holds bf16(x) for layer 0
    u16*   aggbuf  = (u16*)alloc((size_t)M * 128 * 2);
    float* pre     = (float*)alloc((size_t)M * 128 * 4);

    // --- CSR build (once per call; ws is re-poisoned every launch) ---
    hipMemsetAsync(cnt, 0, (size_t)M * 4, stream);
    hist_kernel<<<(E + 255) / 256, 256, 0, stream>>>(dst, cnt, E);
    int NB = (M + 1023) / 1024;
    scan_chunk_kernel<<<NB, 1024, 0, stream>>>(cnt, scn, bsum, M);
    scan_sums_kernel<<<1, 1024, 0, stream>>>(bsum, NB);
    finalize_kernel<<<(M + 255) / 256, 256, 0, stream>>>(cnt, scn, bsum, indptr, cursor, invdeg, M);
    fill_kernel<<<(E + 255) / 256, 256, 0, stream>>>(src, dst, cursor, esrc, E);

    // --- convert x (f32) to bf16 into hbuf; pack weights f32->bf16 B[n][k] ---
    cvt_kernel<<<((M * 32) + 255) / 256, 256, 0, stream>>>(x, hbuf, M * 32);
    pack_kernel<<<(128 * 256 + 255) / 256, 256, 0, stream>>>(wself[0], wneigh[0], bpack0, 128);
    pack_kernel<<<(128 * 256 + 255) / 256, 256, 0, stream>>>(wself[1], wneigh[1], bpack1, 128);
    pack_kernel<<<(64 * 256 + 255) / 256, 256, 0, stream>>>(wself[2], wneigh[2], bpack2, 64);

    const u16* h = hbuf;
    for (int l = 0; l < 2; ++l){
        agg_kernel<<<(M + 3) / 4, 256, 0, stream>>>(h, indptr, esrc, invdeg, aggbuf, M);
        gemm_kernel<<<dim3((M + 63) / 64, 2), 256, 0, stream>>>(h, aggbuf, bpack[l], bias[l], pre, M, 128);
        hipMemsetAsync(colstat, 0, 256 * 4, stream);
        stats_kernel<<<(M + 399) / 400, 256, 0, stream>>>(pre, colstat, M);
        bnfin_kernel<<<1, 128, 0, stream>>>(colstat, gamma[l], beta[l], 1.0f / (float)M);
        apply_kernel<<<((M * 32) + 255) / 256, 256, 0, stream>>>(pre, colstat, hbuf, M * 32);
        h = hbuf;
    }
    agg_kernel<<<(M + 3) / 4, 256, 0, stream>>>(h, indptr, esrc, invdeg, aggbuf, M);
    gemm_kernel<<<dim3((M + 63) / 64, 1), 256, 0, stream>>>(h, aggbuf, bpack[2], bias[2], pre, M, 64);
    lsm_kernel<<<(M + 3) / 4, 256, 0, stream>>>(pre, (float*)d_out, M);
}